// Round 2
// baseline (2572.121 us; speedup 1.0000x reference)
//
#include <hip/hip_runtime.h>
#include <cstddef>

typedef short short8 __attribute__((ext_vector_type(8)));
typedef float f32x4 __attribute__((ext_vector_type(4)));
typedef unsigned short u16;

// problem dims
#define Bn 512
#define Tn 64
#define En 1024
#define An 32
#define Sn 30
#define Dn 200
#define Hn 200
#define SSn 230
#define OUTC 380

// packed weight regions, element (u16) offsets inside d_ws
// Winp: 320(10kt) x 208(13nt) ; Wgru(gate-interleaved): 416(13kt) x 624(39nt)
// Wimg/Wobsd: 224(7) x 208(13) ; Wims/Wobss: 224(7) x 64(4) ; Wobse: 1024(32) x 208(13)
#define U16_WINP  0
#define U16_WGRU  66560
#define U16_WIMG  326144
#define U16_WOBSD 372736
#define U16_WIMS  419328
#define U16_WOBSS 433664
#define U16_WOBSE 448000
#define U16_TOTAL 660992
#define PREOBS_BYTE_OFF 1321984   // 660992*2, 16B aligned

// short8 (16B) indices of regions
#define WINP8  0
#define WGRU8  8320
#define WIMG8  40768
#define WOBSD8 46592
#define WIMS8  52416
#define WOBSS8 54208
#define WOBSE8 56000

#define DEV static __device__ __forceinline__
#define MFMA(a,b,c) __builtin_amdgcn_mfma_f32_16x16x32_bf16((a),(b),(c),0,0,0)

DEV u16 f2bf(float f) {
  union { float f; unsigned u; } v; v.f = f;
  return (u16)((v.u + 0x7FFFu + ((v.u >> 16) & 1u)) >> 16);
}
DEV float bf2f(u16 h) {
  union { unsigned u; float f; } v; v.u = ((unsigned)h) << 16; return v.f;
}
DEV float elu1(float x)  { return x > 0.f ? x : expm1f(x); }
DEV float sigm(float x)  { return 1.f / (1.f + expf(-x)); }
DEV float splus(float x) { return x > 20.f ? x : log1pf(expf(x)); }

// ---------------------------------------------------------------- pack kernel
// B-fragment order for mfma_f32_16x16x32_bf16:
//   dst[((nt*KT+kt)*64 + lane)*8 + j] = W[kt*32 + (lane>>4)*8 + j][nt*16 + (lane&15)]
DEV void pack_one(const float* src, u16* dst, int li, int KT,
                  int Kr, int Nr, int ldN, int roff) {
  int j = li & 7, lane = (li >> 3) & 63, frag = li >> 9;
  int kt = frag % KT, nt = frag / KT;
  int k = kt * 32 + ((lane >> 4) << 3) + j;
  int n = nt * 16 + (lane & 15);
  float v = (k < Kr && n < Nr) ? src[(size_t)(k + roff) * ldN + n] : 0.f;
  dst[li] = f2bf(v);
}

__global__ __launch_bounds__(256) void k_pack(
    const float* w_inp, const float* w_gru, const float* w_img,
    const float* w_obs, const float* w_ims, const float* w_obss,
    u16* ws) {
  int idx = blockIdx.x * 256 + threadIdx.x;
  if (idx >= U16_TOTAL) return;
  if (idx < U16_WGRU) {
    pack_one(w_inp, ws + U16_WINP, idx, 10, 292, 200, 200, 0);
  } else if (idx < U16_WIMG) {
    // w_gru, gate-interleaved columns: tile nt = 3*g + p holds gate p of d-group g
    int li = idx - U16_WGRU;
    int j = li & 7, lane = (li >> 3) & 63, frag = li >> 9;
    int kt = frag % 13, nt = frag / 13;
    int k = kt * 32 + ((lane >> 4) << 3) + j;
    int c = lane & 15;
    int d = (nt / 3) * 16 + c, p = nt % 3;
    float v = (k < 400 && d < 200) ? w_gru[(size_t)k * 600 + p * 200 + d] : 0.f;
    ws[U16_WGRU + li] = f2bf(v);
  }
  else if (idx < U16_WOBSD) pack_one(w_img,  ws + U16_WIMG,  idx - U16_WIMG,  7, 200, 200, 200, 0);
  else if (idx < U16_WIMS)  pack_one(w_obs,  ws + U16_WOBSD, idx - U16_WOBSD, 7, 200, 200, 200, 0);
  else if (idx < U16_WOBSS) pack_one(w_ims,  ws + U16_WIMS,  idx - U16_WIMS,  7, 200,  60,  60, 0);
  else if (idx < U16_WOBSE) pack_one(w_obss, ws + U16_WOBSS, idx - U16_WOBSS, 7, 200,  60,  60, 0);
  else                      pack_one(w_obs,  ws + U16_WOBSE, idx - U16_WOBSE, 32, 1024, 200, 200, 200);
}

// ------------------------------------------------------------- preobs kernel
// preobs[t*512+b][n<200] = emb[b][t][:] @ w_obs_out[200:1224][:]
__global__ __launch_bounds__(256) void k_preobs(
    const float* __restrict__ emb, const u16* __restrict__ ws,
    float* __restrict__ pre) {
  __shared__ u16 Asm[64 * 72];          // [64 rows][64 k + 8 pad]
  __shared__ short8 Bsm[26 * 64];       // 2 kt x 13 nt fragments
  const short8* Wp = (const short8*)(ws + U16_WOBSE);

  int tid = threadIdx.x, wv = tid >> 6, lane = tid & 63;
  int lrow = lane & 15, quad = lane >> 4;
  int m0 = blockIdx.x * 64;
  int t = m0 >> 9, brow0 = m0 & 511;

  f32x4 acc[13];
  const f32x4 z4 = {0.f, 0.f, 0.f, 0.f};
#pragma unroll
  for (int i = 0; i < 13; ++i) acc[i] = z4;

  for (int kc = 0; kc < 16; ++kc) {     // K chunks of 64
    __syncthreads();
#pragma unroll
    for (int q = 0; q < 4; ++q) {
      int i = tid + q * 256;            // 0..1023 float4s
      int row = i >> 4, c4 = i & 15;
      const float* src = emb + ((size_t)((brow0 + row) * Tn + t)) * En + kc * 64 + c4 * 4;
      float4 v = *(const float4*)src;
      union { u16 h[4]; unsigned long long ll; } p;
      p.h[0] = f2bf(v.x); p.h[1] = f2bf(v.y); p.h[2] = f2bf(v.z); p.h[3] = f2bf(v.w);
      *(unsigned long long*)&Asm[row * 72 + c4 * 4] = p.ll;
    }
    for (int q = 0; q < 7; ++q) {
      int i = tid + q * 256;
      if (i < 1664) {
        int pair = i >> 6, l = i & 63;
        int ktl = pair / 13, nt = pair % 13;
        Bsm[i] = Wp[(nt * 32 + kc * 2 + ktl) * 64 + l];
      }
    }
    __syncthreads();
#pragma unroll
    for (int ktl = 0; ktl < 2; ++ktl) {
      short8 a = *(const short8*)&Asm[(wv * 16 + lrow) * 72 + ktl * 32 + quad * 8];
#pragma unroll
      for (int nt = 0; nt < 13; ++nt)
        acc[nt] = MFMA(a, Bsm[(ktl * 13 + nt) * 64 + lane], acc[nt]);
    }
  }
#pragma unroll
  for (int nt = 0; nt < 13; ++nt) {
    int col = nt * 16 + lrow;
    if (col < 200) {
#pragma unroll
      for (int r = 0; r < 4; ++r) {
        int m = m0 + wv * 16 + quad * 4 + r;
        pre[(size_t)m * 200 + col] = acc[nt][r];
      }
    }
  }
}

// ---------------------------------------------------------------- scan kernel
// 32 blocks x 1024 threads (16 waves); block owns batch rows b0..b0+15 for all
// 64 steps. ALL weights live in VGPRs (loaded once): zero weight traffic in loop.
__global__ __launch_bounds__(1024, 4) void k_scan(
    const float* __restrict__ g_ctx, const float* __restrict__ g_act,
    const float* __restrict__ g_np, const float* __restrict__ g_no,
    const float* __restrict__ b_inp, const float* __restrict__ b_gru,
    const float* __restrict__ b_img, const float* __restrict__ b_obs,
    const float* __restrict__ b_ims, const float* __restrict__ b_obss,
    const u16* __restrict__ ws, const float* __restrict__ pre,
    float* __restrict__ out) {

  __shared__ u16 gin[16 * 424];   // cols: 0..199 x, 200..399 deter, 400..423 pad0
  __shared__ u16 Uin[16 * 344];   // cols: 0..29 stoch, 30..259 ctx, 260..291 act, 292..319 pad0
  __shared__ u16 hA[16 * 232];    // h  (prior),  cols 200..231 pad0
  __shared__ u16 hoA[16 * 232];   // ho (posterior)
  __shared__ float stp[16 * 66];
  __shared__ float sto[16 * 66];

  const int tid = threadIdx.x, wv = tid >> 6, lane = tid & 63;
  const int lrow = lane & 15, quad = lane >> 4;
  const int b0 = blockIdx.x * 16;
  const f32x4 z4 = {0.f, 0.f, 0.f, 0.f};
  const short8* Wb = (const short8*)ws;

  // role assignment (wave-uniform)
  const bool actA  = wv < 13;
  const bool actB  = wv < 13;
  const bool actC1 = (wv < 7) || (wv >= 13);
  const bool actD  = wv >= 8;
  const int ntA = actA ? wv : 12;
  const int gB  = actB ? wv : 12;
  const int j0  = wv;                                        // C slot0 tile (0..15 of 26)
  const int j1  = (wv < 7) ? 16 + wv : (wv >= 13 ? 10 + wv : 25);
  const int eD  = actD ? (wv - 8) : 0;

  // ---- load all weight fragments into registers (once)
  short8 fA[10], fB[3][13], fC[2][7], fD[7];
#pragma unroll
  for (int kt = 0; kt < 10; ++kt) fA[kt] = Wb[WINP8 + (ntA * 10 + kt) * 64 + lane];
#pragma unroll
  for (int p = 0; p < 3; ++p)
#pragma unroll
    for (int kt = 0; kt < 13; ++kt)
      fB[p][kt] = Wb[WGRU8 + ((3 * gB + p) * 13 + kt) * 64 + lane];
  {
    int base0 = (j0 < 13) ? (WIMG8 + j0 * 7 * 64) : (WOBSD8 + (j0 - 13) * 7 * 64);
#pragma unroll
    for (int kt = 0; kt < 7; ++kt) fC[0][kt] = Wb[base0 + kt * 64 + lane];
    int base1 = (j1 < 13) ? (WIMG8 + j1 * 7 * 64) : (WOBSD8 + (j1 - 13) * 7 * 64);
#pragma unroll
    for (int kt = 0; kt < 7; ++kt) fC[1][kt] = Wb[base1 + kt * 64 + lane];
    int based = (eD < 4) ? (WIMS8 + eD * 7 * 64) : (WOBSS8 + (eD - 4) * 7 * 64);
#pragma unroll
    for (int kt = 0; kt < 7; ++kt) fD[kt] = Wb[based + kt * 64 + lane];
  }

  // per-role biases (once)
  const int colA = ntA * 16 + lrow;
  const float bA = (actA && colA < 200) ? b_inp[colA] : 0.f;
  const int dcol = gB * 16 + lrow;
  float bgr = 0.f, bgc = 0.f, bgu = 0.f;
  if (actB && dcol < 200) { bgr = b_gru[dcol]; bgc = b_gru[200 + dcol]; bgu = b_gru[400 + dcol]; }
  const int c0 = (j0 < 13 ? j0 : j0 - 13) * 16 + lrow;
  const float bC0 = (c0 < 200) ? (j0 < 13 ? b_img[c0] : b_obs[c0]) : 0.f;
  const int c1 = (j1 - 13) * 16 + lrow;                      // j1 is always an obsd tile
  const float bC1 = (actC1 && c1 < 200) ? b_obs[c1] : 0.f;
  const int cD = (eD & 3) * 16 + lrow;
  const float bD = (actD && cD < 60) ? (eD < 4 ? b_ims[cD] : b_obss[cD]) : 0.f;

  // loader / epilogue roles
  const int crow = tid >> 6;          // 16 rows, 64 threads each
  const int ci = tid & 63;
  const int nrow = tid / 30, ns = tid - nrow * 30;   // valid when tid<480

  // zero-init carry + pads
  for (int i = tid; i < 16 * 424; i += 1024) gin[i] = 0;
  for (int i = tid; i < 16 * 344; i += 1024) Uin[i] = 0;
  for (int i = tid; i < 16 * 232; i += 1024) { hA[i] = 0; hoA[i] = 0; }

  // prefetch ctx/act for t=0
  float pcx[4]; float pact;
  {
    const float* cr = g_ctx + ((size_t)(b0 + crow) * Tn + 0) * SSn;
#pragma unroll
    for (int s = 0; s < 4; ++s) { int i = ci + s * 64; pcx[s] = (i < SSn) ? cr[i] : 0.f; }
    pact = (ci < An) ? g_act[((size_t)(b0 + crow) * Tn + 0) * An + ci] : 0.f;
  }
  __syncthreads();   // init done

  for (int t = 0; t < Tn; ++t) {
    // ---- write prefetched ctx/act into Uin
#pragma unroll
    for (int s = 0; s < 4; ++s) {
      int i = ci + s * 64;
      if (i < SSn) Uin[crow * 344 + 30 + i] = f2bf(pcx[s]);
    }
    if (ci < An) Uin[crow * 344 + 260 + ci] = f2bf(pact);

    // ---- prefetch noise + preobs for THIS step (consumed stages later)
    float vnp = 0.f, vno = 0.f;
    if (tid < 480) {
      size_t ni = ((size_t)t * Bn + b0 + nrow) * Sn + ns;
      vnp = g_np[ni]; vno = g_no[ni];
    }
    float pr0[4] = {0.f, 0.f, 0.f, 0.f}, pr1[4] = {0.f, 0.f, 0.f, 0.f};
    if (wv >= 13) {
#pragma unroll
      for (int r = 0; r < 4; ++r)
        pr0[r] = pre[((size_t)t * Bn + b0 + quad * 4 + r) * 200 + c0];
    }
    if (actC1 && c1 < 200) {
#pragma unroll
      for (int r = 0; r < 4; ++r)
        pr1[r] = pre[((size_t)t * Bn + b0 + quad * 4 + r) * 200 + c1];
    }
    // ---- prefetch ctx/act for NEXT step
    if (t + 1 < Tn) {
      const float* cr = g_ctx + ((size_t)(b0 + crow) * Tn + (t + 1)) * SSn;
#pragma unroll
      for (int s = 0; s < 4; ++s) { int i = ci + s * 64; pcx[s] = (i < SSn) ? cr[i] : 0.f; }
      pact = (ci < An) ? g_act[((size_t)(b0 + crow) * Tn + (t + 1)) * An + ci] : 0.f;
    }
    __syncthreads();   // B1: Uin ready

    // ---- stage A: x = elu([stoch,ctx,act] @ w_inp + b) -> gin[:,0:200]
    if (actA) {
      f32x4 acc = z4;
#pragma unroll
      for (int kt = 0; kt < 10; ++kt) {
        short8 a = *(const short8*)&Uin[lrow * 344 + kt * 32 + quad * 8];
        acc = MFMA(a, fA[kt], acc);
      }
      if (colA < 200) {
#pragma unroll
        for (int r = 0; r < 4; ++r)
          gin[(quad * 4 + r) * 424 + colA] = f2bf(elu1(acc[r] + bA));
      }
    }
    __syncthreads();   // B2: gin.x ready

    // ---- stage B reads (all of [x, deter_old]) into regs
    short8 ab[13];
    if (actB) {
#pragma unroll
      for (int kt = 0; kt < 13; ++kt)
        ab[kt] = *(const short8*)&gin[lrow * 424 + kt * 32 + quad * 8];
    }
    __syncthreads();   // B3: reads of old deter done before overwrite

    // ---- stage B MFMA + fused GRU (gates stay fp32 in accs)
    if (actB) {
      f32x4 ar = z4, ac_ = z4, au = z4;
#pragma unroll
      for (int kt = 0; kt < 13; ++kt) ar  = MFMA(ab[kt], fB[0][kt], ar);
#pragma unroll
      for (int kt = 0; kt < 13; ++kt) ac_ = MFMA(ab[kt], fB[1][kt], ac_);
#pragma unroll
      for (int kt = 0; kt < 13; ++kt) au  = MFMA(ab[kt], fB[2][kt], au);
      if (dcol < 200) {
#pragma unroll
        for (int r = 0; r < 4; ++r) {
          int row = quad * 4 + r;
          float rs   = sigm(ar[r] + bgr);
          float cnd  = tanhf(rs * (ac_[r] + bgc));
          float up   = sigm(au[r] + bgu - 1.f);
          float dold = bf2f(gin[row * 424 + 200 + dcol]);
          float dn   = up * cnd + (1.f - up) * dold;
          gin[row * 424 + 200 + dcol] = f2bf(dn);
          __builtin_nontemporal_store(dn, &out[((size_t)(b0 + row) * Tn + t) * OUTC + 180 + dcol]);
        }
      }
    }
    __syncthreads();   // B4: deter_new ready

    // ---- stage C: h = elu(deter@Wimg+b), ho = elu(deter@Wobsd + pre + b)
    {
      short8 ad[7];
#pragma unroll
      for (int kt = 0; kt < 7; ++kt)
        ad[kt] = *(const short8*)&gin[lrow * 424 + 200 + kt * 32 + quad * 8];
      f32x4 a0 = z4;
#pragma unroll
      for (int kt = 0; kt < 7; ++kt) a0 = MFMA(ad[kt], fC[0][kt], a0);
      if (c0 < 200) {
        if (j0 < 13) {
#pragma unroll
          for (int r = 0; r < 4; ++r)
            hA[(quad * 4 + r) * 232 + c0] = f2bf(elu1(a0[r] + bC0));
        } else {
#pragma unroll
          for (int r = 0; r < 4; ++r)
            hoA[(quad * 4 + r) * 232 + c0] = f2bf(elu1(a0[r] + bC0 + pr0[r]));
        }
      }
      if (actC1) {
        f32x4 a1 = z4;
#pragma unroll
        for (int kt = 0; kt < 7; ++kt) a1 = MFMA(ad[kt], fC[1][kt], a1);
        if (c1 < 200) {
#pragma unroll
          for (int r = 0; r < 4; ++r)
            hoA[(quad * 4 + r) * 232 + c1] = f2bf(elu1(a1[r] + bC1 + pr1[r]));
        }
      }
    }
    __syncthreads();   // B5

    // ---- stage D: st = h@Wims+b, so = ho@Wobss+b
    if (actD) {
      const u16* src = (eD < 4) ? hA : hoA;
      f32x4 acc = z4;
#pragma unroll
      for (int kt = 0; kt < 7; ++kt) {
        short8 a = *(const short8*)&src[lrow * 232 + kt * 32 + quad * 8];
        acc = MFMA(a, fD[kt], acc);
      }
      if (cD < 60) {
        float* dst = (eD < 4) ? stp : sto;
#pragma unroll
        for (int r = 0; r < 4; ++r) dst[(quad * 4 + r) * 66 + cD] = acc[r] + bD;
      }
    }
    __syncthreads();   // B6

    // ---- epilogue: stats + noise + outputs + next stoch
    if (tid < 480) {
      size_t ob = ((size_t)(b0 + nrow) * Tn + t) * OUTC;
      float pm  = stp[nrow * 66 + ns];
      float ps  = splus(stp[nrow * 66 + 30 + ns]) + 0.1f;
      float pst = pm + ps * vnp;
      float om  = sto[nrow * 66 + ns];
      float os  = splus(sto[nrow * 66 + 30 + ns]) + 0.1f;
      float ost = om + os * vno;
      __builtin_nontemporal_store(om,  &out[ob + ns]);
      __builtin_nontemporal_store(os,  &out[ob + 30 + ns]);
      __builtin_nontemporal_store(ost, &out[ob + 60 + ns]);
      __builtin_nontemporal_store(pm,  &out[ob + 90 + ns]);
      __builtin_nontemporal_store(ps,  &out[ob + 120 + ns]);
      __builtin_nontemporal_store(pst, &out[ob + 150 + ns]);
      Uin[nrow * 344 + ns] = f2bf(ost);     // stoch carry for next step
    }
    // no barrier needed: next-top Uin writes are to disjoint cols; B1 guards reads
  }
}

extern "C" void kernel_launch(void* const* d_in, const int* in_sizes, int n_in,
                              void* d_out, int out_size, void* d_ws, size_t ws_size,
                              hipStream_t stream) {
  (void)in_sizes; (void)n_in; (void)out_size; (void)ws_size;
  const float* emb    = (const float*)d_in[0];
  const float* action = (const float*)d_in[1];
  const float* ctx    = (const float*)d_in[2];
  const float* np_    = (const float*)d_in[3];
  const float* no_    = (const float*)d_in[4];
  const float* w_inp  = (const float*)d_in[5];
  const float* b_inp  = (const float*)d_in[6];
  const float* w_gru  = (const float*)d_in[7];
  const float* b_gru  = (const float*)d_in[8];
  const float* w_img  = (const float*)d_in[9];
  const float* b_img  = (const float*)d_in[10];
  const float* w_obs  = (const float*)d_in[11];
  const float* b_obs  = (const float*)d_in[12];
  const float* w_ims  = (const float*)d_in[13];
  const float* b_ims  = (const float*)d_in[14];
  const float* w_obss = (const float*)d_in[15];
  const float* b_obss = (const float*)d_in[16];

  u16*   wsu = (u16*)d_ws;
  float* pre = (float*)((char*)d_ws + PREOBS_BYTE_OFF);
  float* out = (float*)d_out;

  k_pack<<<2582, 256, 0, stream>>>(w_inp, w_gru, w_img, w_obs, w_ims, w_obss, wsu);
  k_preobs<<<512, 256, 0, stream>>>(emb, wsu, pre);
  k_scan<<<32, 1024, 0, stream>>>(ctx, action, np_, no_,
                                  b_inp, b_gru, b_img, b_obs, b_ims, b_obss,
                                  wsu, pre, out);
}

// Round 4
// 1227.198 us; speedup vs baseline: 2.0959x; 2.0959x over previous
//
#include <hip/hip_runtime.h>
#include <cstddef>

typedef short short8 __attribute__((ext_vector_type(8)));
typedef float f32x4 __attribute__((ext_vector_type(4)));
typedef unsigned short u16;

// problem dims
#define Bn 512
#define Tn 64
#define En 1024
#define An 32
#define Sn 30
#define Dn 200
#define SSn 230
#define OUTC 380

// packed weight regions, u16 element offsets inside d_ws
#define U16_WINP0  0
#define U16_WINPCA 6656
#define U16_WGRU   66560
#define U16_WIMG   326144
#define U16_WOBSD  372736
#define U16_WIMS   419328
#define U16_WOBSS  433664
#define U16_WOBSE  448000
#define U16_PREO   660992      // pre_obs bf16 [T*B,200]  (b_obs folded)
#define U16_PREI   7214592     // pre_inp bf16 [T*B,200]  (b_inp folded)

// short8 indices (u16/8)
#define WINP0_8  0
#define WINPCA_8 832
#define WGRU_8   8320
#define WIMG_8   40768
#define WOBSD_8  46592
#define WIMS_8   52416
#define WOBSS_8  54208
#define WOBSE_8  56000

#define DEV static __device__ __forceinline__
#define MFMA(a,b,c) __builtin_amdgcn_mfma_f32_16x16x32_bf16((a),(b),(c),0,0,0)

DEV u16 f2bf(float f) {
  union { float f; unsigned u; } v; v.f = f;
  return (u16)((v.u + 0x7FFFu + ((v.u >> 16) & 1u)) >> 16);
}
DEV float bf2f(u16 h) {
  union { unsigned u; float f; } v; v.u = ((unsigned)h) << 16; return v.f;
}
// fast native transcendentals (v_exp_f32 / v_log_f32 / v_rcp_f32)
DEV float fexp(float x)  { return __builtin_amdgcn_exp2f(x * 1.44269504f); }
DEV float sigm(float x)  { return __builtin_amdgcn_rcpf(1.f + fexp(-x)); }
DEV float tanhf_(float x){ return 1.f - 2.f * __builtin_amdgcn_rcpf(fexp(2.f * x) + 1.f); }
DEV float elu1(float x)  { return x > 0.f ? x : fexp(x) - 1.f; }
DEV float splus(float x) { return 0.69314718f * __builtin_amdgcn_logf(1.f + fexp(x)); }

// ---------------------------------------------------------------- pack kernel
// One block per (region, nt) strip; LDS-staged, coalesced reads along rows.
// B-fragment order: frag (nt*KT+kt): el[lane*8+j] = W[kt*32+(lane>>4)*8+j][nt*16+(lane&15)]
__global__ __launch_bounds__(256) void k_pack2(
    const float* __restrict__ w_inp, const float* __restrict__ w_gru,
    const float* __restrict__ w_img, const float* __restrict__ w_obs,
    const float* __restrict__ w_ims, const float* __restrict__ w_obss,
    u16* __restrict__ ws) {
  int s = blockIdx.x;
  const float* src; int KT, Kr, ldN, roff, colbase, cmax; size_t dstbase; int ntKT;
  if (s < 13)      { src=w_inp;  KT=1;  Kr=30;   ldN=200; roff=0;   int nt=s;    colbase=nt*16; cmax=min(16,200-colbase); dstbase=U16_WINP0;  ntKT=nt*KT; }
  else if (s < 26) { src=w_inp;  KT=9;  Kr=262;  ldN=200; roff=30;  int nt=s-13; colbase=nt*16; cmax=min(16,200-colbase); dstbase=U16_WINPCA; ntKT=nt*KT; }
  else if (s < 65) { src=w_gru;  KT=13; Kr=400;  ldN=600; roff=0;   int ntp=s-26; int g=ntp/3, p=ntp%3;
                     colbase=p*200+g*16; cmax=min(16,200-g*16); dstbase=U16_WGRU; ntKT=ntp*KT; }
  else if (s < 78) { src=w_img;  KT=7;  Kr=200;  ldN=200; roff=0;   int nt=s-65; colbase=nt*16; cmax=min(16,200-colbase); dstbase=U16_WIMG;  ntKT=nt*KT; }
  else if (s < 91) { src=w_obs;  KT=7;  Kr=200;  ldN=200; roff=0;   int nt=s-78; colbase=nt*16; cmax=min(16,200-colbase); dstbase=U16_WOBSD; ntKT=nt*KT; }
  else if (s < 95) { src=w_ims;  KT=7;  Kr=200;  ldN=60;  roff=0;   int nt=s-91; colbase=nt*16; cmax=min(16,60-colbase);  dstbase=U16_WIMS;  ntKT=nt*KT; }
  else if (s < 99) { src=w_obss; KT=7;  Kr=200;  ldN=60;  roff=0;   int nt=s-95; colbase=nt*16; cmax=min(16,60-colbase);  dstbase=U16_WOBSS; ntKT=nt*KT; }
  else             { src=w_obs;  KT=32; Kr=1024; ldN=200; roff=200; int nt=s-99; colbase=nt*16; cmax=min(16,200-colbase); dstbase=U16_WOBSE; ntKT=nt*KT; }

  __shared__ float Ws[2048];       // 128 k-rows x 16 cols
  int tid = threadIdx.x;
  int nchunk = (KT + 3) >> 2;
  for (int kc = 0; kc < nchunk; ++kc) {
    __syncthreads();
    for (int i = tid; i < 2048; i += 256) {
      int r = i >> 4, c = i & 15;
      int k = kc * 128 + r;
      Ws[i] = (k < Kr && c < cmax) ? src[(size_t)(roff + k) * ldN + colbase + c] : 0.f;
    }
    __syncthreads();
    int nf = KT - kc * 4; if (nf > 4) nf = 4;
    int fi = tid >> 6, lane = tid & 63;
    if (fi < nf) {
      int kt = kc * 4 + fi;
      union { u16 h[8]; short8 v; } pk;
#pragma unroll
      for (int j = 0; j < 8; ++j)
        pk.h[j] = f2bf(Ws[(fi * 32 + ((lane >> 4) << 3) + j) * 16 + (lane & 15)]);
      *(short8*)&ws[dstbase + (size_t)(ntKT + kt) * 512 + lane * 8] = pk.v;
    }
  }
}

// ---------------------------------------------------------------- pre kernel
// pre_obs[t*512+b][n] = emb[b][t][:]@Wobse + b_obs    (bf16)
// pre_inp[t*512+b][n] = [ctx|act][b][t][:]@Winpca + b_inp  (bf16)
__global__ __launch_bounds__(256) void k_pre(
    const float* __restrict__ emb, const float* __restrict__ ctx,
    const float* __restrict__ act, const float* __restrict__ b_obs,
    const float* __restrict__ b_inp, u16* __restrict__ ws) {
  __shared__ u16 Asm[64 * 72];
  __shared__ short8 Bsm[26 * 64];
  const short8* Wb = (const short8*)ws;
  u16* preO = ws + U16_PREO;
  u16* preI = ws + U16_PREI;

  int tid = threadIdx.x, wv = tid >> 6, lane = tid & 63;
  int lrow = lane & 15, quad = lane >> 4;
  int m0 = blockIdx.x * 64;
  int t = m0 >> 9, b0 = m0 & 511;

  const f32x4 z4 = {0.f, 0.f, 0.f, 0.f};
  f32x4 acc[13];

  // ---------------- job 1: obs (K=1024 from emb)
#pragma unroll
  for (int i = 0; i < 13; ++i) acc[i] = z4;
  for (int kc = 0; kc < 16; ++kc) {
    __syncthreads();
#pragma unroll
    for (int q = 0; q < 4; ++q) {
      int i = tid + q * 256;
      int row = i >> 4, c4 = i & 15;
      const float* src = emb + ((size_t)((b0 + row) * Tn + t)) * En + kc * 64 + c4 * 4;
      float4 v = *(const float4*)src;
      union { u16 h[4]; unsigned long long ll; } p;
      p.h[0] = f2bf(v.x); p.h[1] = f2bf(v.y); p.h[2] = f2bf(v.z); p.h[3] = f2bf(v.w);
      *(unsigned long long*)&Asm[row * 72 + c4 * 4] = p.ll;
    }
    for (int q = 0; q < 7; ++q) {
      int i = tid + q * 256;
      if (i < 1664) {
        int pair = i >> 6, l = i & 63;
        int ktl = pair / 13, nt = pair % 13;
        Bsm[i] = Wb[WOBSE_8 + (size_t)(nt * 32 + kc * 2 + ktl) * 64 + l];
      }
    }
    __syncthreads();
#pragma unroll
    for (int ktl = 0; ktl < 2; ++ktl) {
      short8 a = *(const short8*)&Asm[(wv * 16 + lrow) * 72 + ktl * 32 + quad * 8];
#pragma unroll
      for (int nt = 0; nt < 13; ++nt)
        acc[nt] = MFMA(a, Bsm[(ktl * 13 + nt) * 64 + lane], acc[nt]);
    }
  }
#pragma unroll
  for (int nt = 0; nt < 13; ++nt) {
    int col = nt * 16 + lrow;
    if (col < 200) {
      float bias = b_obs[col];
#pragma unroll
      for (int r = 0; r < 4; ++r) {
        int m = t * 512 + b0 + wv * 16 + quad * 4 + r;
        preO[(size_t)m * 200 + col] = f2bf(acc[nt][r] + bias);
      }
    }
  }

  // ---------------- job 2: inp (K=262 from [ctx|act])
#pragma unroll
  for (int i = 0; i < 13; ++i) acc[i] = z4;
  for (int kc = 0; kc < 5; ++kc) {
    __syncthreads();
#pragma unroll
    for (int q = 0; q < 4; ++q) {
      int i = tid + q * 256;
      int row = i >> 4, c4 = i & 15;
      union { u16 h[4]; unsigned long long ll; } p;
#pragma unroll
      for (int e = 0; e < 4; ++e) {
        int k = kc * 64 + c4 * 4 + e;
        float v = 0.f;
        if (k < 230)      v = ctx[((size_t)(b0 + row) * Tn + t) * SSn + k];
        else if (k < 262) v = act[((size_t)(b0 + row) * Tn + t) * An + (k - 230)];
        p.h[e] = f2bf(v);
      }
      *(unsigned long long*)&Asm[row * 72 + c4 * 4] = p.ll;
    }
    int nktl = (kc < 4) ? 2 : 1;
    for (int q = 0; q < 7; ++q) {
      int i = tid + q * 256;
      if (i < nktl * 13 * 64) {
        int pair = i >> 6, l = i & 63;
        int ktl = pair / 13, nt = pair % 13;
        Bsm[i] = Wb[WINPCA_8 + (size_t)(nt * 9 + kc * 2 + ktl) * 64 + l];
      }
    }
    __syncthreads();
    for (int ktl = 0; ktl < nktl; ++ktl) {
      short8 a = *(const short8*)&Asm[(wv * 16 + lrow) * 72 + ktl * 32 + quad * 8];
#pragma unroll
      for (int nt = 0; nt < 13; ++nt)
        acc[nt] = MFMA(a, Bsm[(ktl * 13 + nt) * 64 + lane], acc[nt]);
    }
  }
#pragma unroll
  for (int nt = 0; nt < 13; ++nt) {
    int col = nt * 16 + lrow;
    if (col < 200) {
      float bias = b_inp[col];
#pragma unroll
      for (int r = 0; r < 4; ++r) {
        int m = t * 512 + b0 + wv * 16 + quad * 4 + r;
        preI[(size_t)m * 200 + col] = f2bf(acc[nt][r] + bias);
      }
    }
  }
}

// ---------------------------------------------------------------- scan kernel
// 32 blocks x 512 threads (8 waves); block owns 16 batch rows, 64 steps.
// Critical path only: A (stoch-part of input MLP), B+GRU (fused), C-obs, D-obs.
// deter double-buffered by parity in AB; 5 barriers/step.
__global__ __launch_bounds__(512, 2) void k_scan(
    const float* __restrict__ g_no, const float* __restrict__ b_gru,
    const float* __restrict__ b_obss, const u16* __restrict__ ws,
    float* __restrict__ out) {

  // AB row layout (u16, stride 872): parity p at p*424: [x 0..199 | deter 200..423]
  __shared__ u16 AB[16 * 872];
  __shared__ u16 Uin[16 * 40];      // stoch (cols 0..29; 30,31 multiply zero B rows)
  __shared__ u16 hoA[16 * 232];     // ho; cols 200..231 MUST stay zero (K-pads)
  __shared__ float sto[16 * 66];

  const short8* Wb = (const short8*)ws;
  const u16* preO = ws + U16_PREO;
  const u16* preI = ws + U16_PREI;

  const int tid = threadIdx.x, wv = tid >> 6, lane = tid & 63;
  const int lrow = lane & 15, quad = lane >> 4;
  const int b0 = blockIdx.x * 16;
  const f32x4 z4 = {0.f, 0.f, 0.f, 0.f};

  // roles
  const bool two = wv < 5;               // waves 0-4 take a second tile (idx wv+8)
  const int colA0 = wv * 16 + lrow;
  const int colA1 = (wv + 8) * 16 + lrow;
  const int dcol0 = colA0;
  const int dcol1 = colA1;
  const int nrow = tid / 30, ns = tid - nrow * 30;   // epilogue role (tid<480)

  // park stage-A fragments
  short8 fA0 = Wb[WINP0_8 + (size_t)wv * 64 + lane];
  short8 fA1 = two ? Wb[WINP0_8 + (size_t)(wv + 8) * 64 + lane] : fA0;

  // per-role biases
  float bgr0 = b_gru[dcol0], bgc0 = b_gru[200 + dcol0], bgu0 = b_gru[400 + dcol0];
  float bgr1 = 0.f, bgc1 = 0.f, bgu1 = 0.f;
  if (two && dcol1 < 200) { bgr1 = b_gru[dcol1]; bgc1 = b_gru[200 + dcol1]; bgu1 = b_gru[400 + dcol1]; }
  const int cD = (wv & 3) * 16 + lrow;
  const float bD = (wv < 4 && cD < 60) ? b_obss[cD] : 0.f;

  // zero init ALL carry/pad regions (NaN-safety: MFMA propagates NaN*0)
  for (int i = tid; i < 16 * 872; i += 512) AB[i] = 0;
  for (int i = tid; i < 16 * 40; i += 512) Uin[i] = 0;
  for (int i = tid; i < 16 * 232; i += 512) hoA[i] = 0;
  __syncthreads();

  for (int t = 0; t < Tn; ++t) {
    const int par = t & 1;
    const int pb = par * 424, qb = 424 - pb;

    // ---- prefetches for this step (global, consumed after later barriers)
    u16 pin0[4], pin1[4] = {0,0,0,0}, pob0[4], pob1[4] = {0,0,0,0};
    {
      size_t mb = (size_t)t * 512 + b0 + quad * 4;
#pragma unroll
      for (int r = 0; r < 4; ++r) pin0[r] = preI[(mb + r) * 200 + colA0];
      if (two && colA1 < 200) {
#pragma unroll
        for (int r = 0; r < 4; ++r) pin1[r] = preI[(mb + r) * 200 + colA1];
      }
#pragma unroll
      for (int r = 0; r < 4; ++r) pob0[r] = preO[(mb + r) * 200 + colA0];
      if (two && colA1 < 200) {
#pragma unroll
        for (int r = 0; r < 4; ++r) pob1[r] = preO[(mb + r) * 200 + colA1];
      }
    }
    float vno = 0.f;
    if (tid < 480) vno = g_no[((size_t)t * 512 + b0 + nrow) * Sn + ns];

    __syncthreads();   // B1: Uin stoch ready (epilogue of t-1)

    // ---- stage A: x = elu(stoch @ W0 + pre_inp)
    {
      short8 aU = *(const short8*)&Uin[lrow * 40 + quad * 8];
      f32x4 a0 = MFMA(aU, fA0, z4);
#pragma unroll
      for (int r = 0; r < 4; ++r)
        AB[(quad * 4 + r) * 872 + pb + colA0] = f2bf(elu1(a0[r] + bf2f(pin0[r])));
      if (two) {
        f32x4 a1 = MFMA(aU, fA1, z4);
        if (colA1 < 200) {
#pragma unroll
          for (int r = 0; r < 4; ++r)
            AB[(quad * 4 + r) * 872 + pb + colA1] = f2bf(elu1(a1[r] + bf2f(pin1[r])));
        }
      }
    }
    __syncthreads();   // B2: x ready

    // ---- stage B: gates + fused GRU; writes deter_new to parity^1
    {
      short8 ax[13];
#pragma unroll
      for (int kt = 0; kt < 13; ++kt)
        ax[kt] = *(const short8*)&AB[lrow * 872 + pb + kt * 32 + quad * 8];
      const int ng = two ? 2 : 1;
      for (int gi = 0; gi < ng; ++gi) {
        int g = wv + 8 * gi;
        int dcol = gi ? dcol1 : dcol0;
        float br = gi ? bgr1 : bgr0, bc = gi ? bgc1 : bgc0, bu = gi ? bgu1 : bgu0;
        const short8* bpr = Wb + WGRU_8 + (size_t)((3 * g + 0) * 13) * 64 + lane;
        const short8* bpc = Wb + WGRU_8 + (size_t)((3 * g + 1) * 13) * 64 + lane;
        const short8* bpu = Wb + WGRU_8 + (size_t)((3 * g + 2) * 13) * 64 + lane;
        f32x4 ar = z4, ac = z4, au = z4;
#pragma unroll
        for (int kt = 0; kt < 13; ++kt) ar = MFMA(ax[kt], bpr[kt * 64], ar);
#pragma unroll
        for (int kt = 0; kt < 13; ++kt) ac = MFMA(ax[kt], bpc[kt * 64], ac);
#pragma unroll
        for (int kt = 0; kt < 13; ++kt) au = MFMA(ax[kt], bpu[kt * 64], au);
        if (dcol < 200) {
#pragma unroll
          for (int r = 0; r < 4; ++r) {
            int row = quad * 4 + r;
            float dold = bf2f(AB[row * 872 + pb + 200 + dcol]);
            float rs = sigm(ar[r] + br);
            float cnd = tanhf_(rs * (ac[r] + bc));
            float up = sigm(au[r] + bu - 1.f);
            float dn = up * cnd + (1.f - up) * dold;
            AB[row * 872 + qb + 200 + dcol] = f2bf(dn);
            __builtin_nontemporal_store(dn, &out[((size_t)(b0 + row) * Tn + t) * OUTC + 180 + dcol]);
          }
        }
      }
    }
    __syncthreads();   // B3: deter_new ready

    // ---- stage C: ho = elu(deter_new @ Wobsd + pre_obs)
    {
      short8 ad[7];
#pragma unroll
      for (int kt = 0; kt < 7; ++kt)
        ad[kt] = *(const short8*)&AB[lrow * 872 + qb + 200 + kt * 32 + quad * 8];
      {
        const short8* bp = Wb + WOBSD_8 + (size_t)(wv * 7) * 64 + lane;
        f32x4 a0 = z4;
#pragma unroll
        for (int kt = 0; kt < 7; ++kt) a0 = MFMA(ad[kt], bp[kt * 64], a0);
#pragma unroll
        for (int r = 0; r < 4; ++r)
          hoA[(quad * 4 + r) * 232 + colA0] = f2bf(elu1(a0[r] + bf2f(pob0[r])));
      }
      if (two && colA1 < 200) {
        const short8* bp = Wb + WOBSD_8 + (size_t)((wv + 8) * 7) * 64 + lane;
        f32x4 a1 = z4;
#pragma unroll
        for (int kt = 0; kt < 7; ++kt) a1 = MFMA(ad[kt], bp[kt * 64], a1);
#pragma unroll
        for (int r = 0; r < 4; ++r)
          hoA[(quad * 4 + r) * 232 + colA1] = f2bf(elu1(a1[r] + bf2f(pob1[r])));
      }
    }
    __syncthreads();   // B4: ho ready

    // ---- stage D: so = ho @ Wobss + b  (waves 0-3)
    if (wv < 4) {
      const short8* bp = Wb + WOBSS_8 + (size_t)(wv * 7) * 64 + lane;
      f32x4 acc = z4;
#pragma unroll
      for (int kt = 0; kt < 7; ++kt) {
        short8 a = *(const short8*)&hoA[lrow * 232 + kt * 32 + quad * 8];
        acc = MFMA(a, bp[kt * 64], acc);
      }
      if (cD < 60) {
#pragma unroll
        for (int r = 0; r < 4; ++r) sto[(quad * 4 + r) * 66 + cD] = acc[r] + bD;
      }
    }
    __syncthreads();   // B5: so ready

    // ---- epilogue: posterior stats + next stoch
    if (tid < 480) {
      size_t ob = ((size_t)(b0 + nrow) * Tn + t) * OUTC;
      float om = sto[nrow * 66 + ns];
      float os = splus(sto[nrow * 66 + 30 + ns]) + 0.1f;
      float ost = om + os * vno;
      __builtin_nontemporal_store(om,  &out[ob + ns]);
      __builtin_nontemporal_store(os,  &out[ob + 30 + ns]);
      __builtin_nontemporal_store(ost, &out[ob + 60 + ns]);
      Uin[nrow * 40 + ns] = f2bf(ost);
    }
    // loop-top B1 guards Uin/A-region reuse
  }
}

// ---------------------------------------------------------------- prior kernel
// Wide post-pass: h = elu(deter@Wimg+b), st = h@Wims+b, pm/ps/pst -> out[90..180)
__global__ __launch_bounds__(256) void k_prior(
    const float* __restrict__ g_np, const float* __restrict__ b_img,
    const float* __restrict__ b_ims, const u16* __restrict__ ws,
    float* __restrict__ out) {
  __shared__ u16 Ad[64 * 232];
  __shared__ u16 Ah[64 * 232];
  __shared__ float stf[64 * 66];
  const short8* Wb = (const short8*)ws;

  int tid = threadIdx.x, wv = tid >> 6, lane = tid & 63;
  int lrow = lane & 15, quad = lane >> 4;
  int b = blockIdx.x;                 // 64 rows = all t for batch row b
  const f32x4 z4 = {0.f, 0.f, 0.f, 0.f};

  // zero-init (K-pad cols 200..231 are read by MFMA; NaN-safety)
  for (int i = tid; i < 64 * 232; i += 256) { Ad[i] = 0; Ah[i] = 0; }
  __syncthreads();

  // stage deter (fp32 from out) -> bf16 LDS
  for (int idx = tid; idx < 64 * 200; idx += 256) {
    int row = idx / 200, col = idx - row * 200;
    Ad[row * 232 + col] = f2bf(out[((size_t)b * Tn + row) * OUTC + 180 + col]);
  }
  __syncthreads();

  // GEMM1: h = elu(deter @ Wimg + b_img)
  {
    short8 af[7];
#pragma unroll
    for (int kt = 0; kt < 7; ++kt)
      af[kt] = *(const short8*)&Ad[(wv * 16 + lrow) * 232 + kt * 32 + quad * 8];
    for (int nt = 0; nt < 13; ++nt) {
      const short8* bp = Wb + WIMG_8 + (size_t)(nt * 7) * 64 + lane;
      f32x4 acc = z4;
#pragma unroll
      for (int kt = 0; kt < 7; ++kt) acc = MFMA(af[kt], bp[kt * 64], acc);
      int col = nt * 16 + lrow;
      if (col < 200) {
        float bias = b_img[col];
#pragma unroll
        for (int r = 0; r < 4; ++r)
          Ah[(wv * 16 + quad * 4 + r) * 232 + col] = f2bf(elu1(acc[r] + bias));
      }
    }
  }
  __syncthreads();

  // GEMM2: st = h @ Wims + b_ims
  {
    short8 ah[7];
#pragma unroll
    for (int kt = 0; kt < 7; ++kt)
      ah[kt] = *(const short8*)&Ah[(wv * 16 + lrow) * 232 + kt * 32 + quad * 8];
#pragma unroll
    for (int nt = 0; nt < 4; ++nt) {
      const short8* bp = Wb + WIMS_8 + (size_t)(nt * 7) * 64 + lane;
      f32x4 acc = z4;
#pragma unroll
      for (int kt = 0; kt < 7; ++kt) acc = MFMA(ah[kt], bp[kt * 64], acc);
      int col = nt * 16 + lrow;
      if (col < 60) {
        float bias = b_ims[col];
#pragma unroll
        for (int r = 0; r < 4; ++r)
          stf[(wv * 16 + quad * 4 + r) * 66 + col] = acc[r] + bias;
      }
    }
  }
  __syncthreads();

  // epilogue: pm/ps/pst
  for (int idx = tid; idx < 64 * 30; idx += 256) {
    int row = idx / 30, s = idx - row * 30;   // row == t
    float pm = stf[row * 66 + s];
    float ps = splus(stf[row * 66 + 30 + s]) + 0.1f;
    float pst = pm + ps * g_np[((size_t)row * 512 + b) * Sn + s];
    size_t ob = ((size_t)b * Tn + row) * OUTC;
    __builtin_nontemporal_store(pm,  &out[ob + 90 + s]);
    __builtin_nontemporal_store(ps,  &out[ob + 120 + s]);
    __builtin_nontemporal_store(pst, &out[ob + 150 + s]);
  }
}

extern "C" void kernel_launch(void* const* d_in, const int* in_sizes, int n_in,
                              void* d_out, int out_size, void* d_ws, size_t ws_size,
                              hipStream_t stream) {
  (void)in_sizes; (void)n_in; (void)out_size; (void)ws_size;
  const float* emb    = (const float*)d_in[0];
  const float* action = (const float*)d_in[1];
  const float* ctx    = (const float*)d_in[2];
  const float* np_    = (const float*)d_in[3];
  const float* no_    = (const float*)d_in[4];
  const float* w_inp  = (const float*)d_in[5];
  const float* b_inp  = (const float*)d_in[6];
  const float* w_gru  = (const float*)d_in[7];
  const float* b_gru  = (const float*)d_in[8];
  const float* w_img  = (const float*)d_in[9];
  const float* b_img  = (const float*)d_in[10];
  const float* w_obs  = (const float*)d_in[11];
  const float* b_obs  = (const float*)d_in[12];
  const float* w_ims  = (const float*)d_in[13];
  const float* b_ims  = (const float*)d_in[14];
  const float* w_obss = (const float*)d_in[15];
  const float* b_obss = (const float*)d_in[16];

  u16* wsu = (u16*)d_ws;
  float* out = (float*)d_out;

  k_pack2<<<112, 256, 0, stream>>>(w_inp, w_gru, w_img, w_obs, w_ims, w_obss, wsu);
  k_pre<<<512, 256, 0, stream>>>(emb, ctx, action, b_obs, b_inp, wsu);
  k_scan<<<32, 512, 0, stream>>>(no_, b_gru, b_obss, wsu, out);
  k_prior<<<512, 256, 0, stream>>>(np_, b_img, b_ims, wsu, out);
}